// Round 9
// baseline (67.084 us; speedup 1.0000x reference)
//
#include <hip/hip_runtime.h>
#include <stdint.h>

#define S_GRID 7
#define N_CH 30
#define MAXB 8192          // max compacted boxes (actual data: 6272)
#define NTILE (MAXB/256)   // 32 j-tiles
#define NCHUNK 64          // i-chunks

// ---- ws layout (bytes) ----
// 0      : int hdr[2]  {ncoord, nb}
// 16     : float acc[4] {xy+wh, obj, nobj, class}
// 48     : int finalCtr
// 64     : int blockCounts[128]   -> 576
// 576    : int blockBase[128]     -> 1088
// 4096   : float4 BP[MAXB]   (131072) -> 135168
// 135168 : float4 BT[MAXB]   (131072) -> 266240
// 266240 : float  ConfP[MAXB] (32768) -> 299008
// 299008 : float  AreaP[MAXB] (32768) -> 331776
// 331776 : u64 pkeys[NCHUNK][MAXB]  (4 MiB)

__global__ void k_count(const float* __restrict__ T, int ncell, int* __restrict__ blockCounts,
                        float* __restrict__ acc, int* __restrict__ finalCtr) {
    // zero-init folded here (a separate fill node costs ~40us)
    if (blockIdx.x == 0) {
        if (threadIdx.x < 4)  acc[threadIdx.x] = 0.0f;
        if (threadIdx.x == 4) *finalCtr = 0;
    }
    int cell = blockIdx.x * 256 + threadIdx.x;
    int obj = 0;
    if (cell < ncell) obj = (T[(size_t)cell * N_CH + 4] == 1.0f);
    unsigned long long b = __ballot(obj);
    __shared__ int wc[4];
    int lane = threadIdx.x & 63, wid = threadIdx.x >> 6;
    if (lane == 0) wc[wid] = __popcll(b);
    __syncthreads();
    if (threadIdx.x == 0) blockCounts[blockIdx.x] = wc[0] + wc[1] + wc[2] + wc[3];
}

// 1 block x 128 threads: shuffle-scan
__global__ void k_scan(const int* __restrict__ blockCounts, int* __restrict__ blockBase,
                       int nblocks, int* __restrict__ hdr) {
    int t = threadIdx.x;                 // 0..127, nblocks <= 128
    int c = (t < nblocks) ? blockCounts[t] : 0;
    int lane = t & 63, w = t >> 6;
    int incl = c;
    #pragma unroll
    for (int o = 1; o < 64; o <<= 1) {
        int v = __shfl_up(incl, o);
        if (lane >= o) incl += v;
    }
    __shared__ int wtot[2];
    if (lane == 63) wtot[w] = incl;
    __syncthreads();
    if (w == 1) incl += wtot[0];
    if (t < nblocks) blockBase[t] = incl - c;
    if (t == nblocks - 1) { hdr[0] = incl; hdr[1] = 2 * incl; }
}

// compaction (exact reference ordering) + cheap masked losses fused
__global__ void k_compact(const float* __restrict__ P, const float* __restrict__ T, int ncell,
                          const int* __restrict__ blockBase,
                          float4* __restrict__ BP, float4* __restrict__ BT,
                          float* __restrict__ ConfP, float* __restrict__ AreaP,
                          float* __restrict__ acc) {
    int cell = blockIdx.x * 256 + threadIdx.x;
    int obj = 0;
    const float* p = P + (size_t)cell * N_CH;
    const float* t = T + (size_t)cell * N_CH;
    if (cell < ncell) obj = (t[4] == 1.0f);
    unsigned long long b = __ballot(obj);
    int lane = threadIdx.x & 63, wid = threadIdx.x >> 6;
    __shared__ int wofs[4];
    if (lane == 0) wofs[wid] = __popcll(b);
    __syncthreads();
    if (threadIdx.x == 0) {
        int s = 0;
        for (int w = 0; w < 4; w++) { int c = wofs[w]; wofs[w] = s; s += c; }
    }
    __syncthreads();

    float cls = 0.f, nobj = 0.f;
    if (cell < ncell) {
        if (obj) {
            #pragma unroll
            for (int k = 10; k < 30; k++) { float d = p[k] - t[k]; cls += d * d; }
        } else {
            float d0 = p[4] - t[4], d1 = p[9] - t[9];
            nobj = d0 * d0 + d1 * d1;
        }
    }
    #pragma unroll
    for (int o = 32; o; o >>= 1) { cls += __shfl_down(cls, o); nobj += __shfl_down(nobj, o); }
    if (lane == 0) {
        if (cls != 0.f)  atomicAdd(&acc[3], cls);
        if (nobj != 0.f) atomicAdd(&acc[2], nobj);
    }

    if (obj) {
        int rank = blockBase[blockIdx.x] + wofs[wid] + __popcll(b & ((1ull << lane) - 1ull));
        #pragma unroll
        for (int bb = 0; bb < 2; ++bb) {
            int m = 2 * rank + bb;
            if (m < MAXB) {
                int o5 = bb * 5;
                float cx = p[o5 + 0] / (float)S_GRID, cy = p[o5 + 1] / (float)S_GRID;
                float w = p[o5 + 2], h = p[o5 + 3];
                float4 bp = make_float4(cx - 0.5f * w, cy - 0.5f * h, cx + 0.5f * w, cy + 0.5f * h);
                BP[m] = bp;
                AreaP[m] = (bp.z - bp.x) * (bp.w - bp.y);
                ConfP[m] = p[4 + o5];
                cx = t[o5 + 0] / (float)S_GRID; cy = t[o5 + 1] / (float)S_GRID;
                w = t[o5 + 2]; h = t[o5 + 3];
                BT[m] = make_float4(cx - 0.5f * w, cy - 0.5f * h, cx + 0.5f * w, cy + 0.5f * h);
            }
        }
    }
}

// R2's empirically-fast match loop, verbatim (rcp-compare form, ternary updates)
__global__ void k_match(const float4* __restrict__ BP, const float4* __restrict__ BT,
                        const float* __restrict__ AreaP,
                        const int* __restrict__ hdr,
                        unsigned long long* __restrict__ pkeys) {
    int nb = hdr[1]; if (nb > MAXB) nb = MAXB;
    int j = blockIdx.x * 256 + threadIdx.x;
    int c = blockIdx.y;
    int chunkLen = (nb + NCHUNK - 1) / NCHUNK;
    int i0 = c * chunkLen;
    int i1 = min(nb, i0 + chunkLen);
    if (j >= nb || i0 >= i1) return;
    float4 tb = BT[j];
    float a2 = (tb.z - tb.x) * (tb.w - tb.y);
    float best = -1.f;
    int bidx = 0;
    for (int i = i0; i < i1; ++i) {
        float4 pb = BP[i];             // wave-uniform -> scalar loads
        float a1 = AreaP[i];
        float lx = fmaxf(pb.x, tb.x), ly = fmaxf(pb.y, tb.y);
        float rx = fminf(pb.z, tb.z), ry = fminf(pb.w, tb.w);
        float wx = fmaxf(rx - lx, 0.f), wy = fmaxf(ry - ly, 0.f);
        float inter = wx * wy;
        float u = a1 + a2 - inter;
        if (inter > best * u) {        // iou > best, without per-iter divide
            float r;                   // approx rcp: rel err ~1e-7; threshold is 0.89 abs
            asm("v_rcp_f32 %0, %1" : "=v"(r) : "v"(u));
            best = inter * r;
            bidx = i;
        }
    }
    pkeys[(size_t)c * MAXB + j] =
        ((unsigned long long)__float_as_uint(best) << 32) |
        (unsigned long long)(0xFFFFFFFFu - (unsigned)bidx);
}

// gather + final combine fused via ACQ_REL election (proven R5-R8; no __threadfence)
__global__ void k_gather(const float4* __restrict__ BP, const float4* __restrict__ BT,
                         const float* __restrict__ ConfP,
                         const int* __restrict__ hdr,
                         const unsigned long long* __restrict__ pkeys,
                         float* __restrict__ acc, int* __restrict__ finalCtr,
                         float* __restrict__ out, float inv_batch) {
    int nb = hdr[1]; if (nb > MAXB) nb = MAXB;
    int tid = threadIdx.x;
    int j = blockIdx.x * 256 + tid;
    float sxywh = 0.f, sobj = 0.f;
    if (j < nb) {
        int chunkLen = (nb + NCHUNK - 1) / NCHUNK;
        unsigned long long key = 0;
        for (int c = 0; c < NCHUNK; ++c) {
            if (c * chunkLen >= nb) break;   // unwritten slots
            unsigned long long k2 = pkeys[(size_t)c * MAXB + j];
            if (k2 > key) key = k2;          // bigger iou wins; ties -> smaller idx
        }
        float iou = __uint_as_float((unsigned)(key >> 32));
        unsigned idx = 0xFFFFFFFFu - (unsigned)(key & 0xFFFFFFFFull);
        float4 bp = BP[idx], bt = BT[idx];
        float cp = ConfP[idx];
        float dx = bp.x - bt.x, dy = bp.y - bt.y;
        float dw = sqrtf(bp.z) - sqrtf(bt.z);
        float dh = sqrtf(bp.w) - sqrtf(bt.w);
        sxywh = dx * dx + dy * dy + dw * dw + dh * dh;
        float dob = cp - iou;
        sobj = dob * dob;
    }
    #pragma unroll
    for (int o = 32; o; o >>= 1) { sxywh += __shfl_down(sxywh, o); sobj += __shfl_down(sobj, o); }
    if ((tid & 63) == 0) {
        if (sxywh != 0.f) atomicAdd(&acc[0], sxywh);
        if (sobj != 0.f)  atomicAdd(&acc[1], sobj);
    }
    __syncthreads();                         // drains wave-leader atomics
    if (tid == 0) {
        int old = __hip_atomic_fetch_add(finalCtr, 1, __ATOMIC_ACQ_REL, __HIP_MEMORY_SCOPE_AGENT);
        if (old == NTILE - 1) {              // last block: all adds visible
            float a0 = __hip_atomic_load(&acc[0], __ATOMIC_RELAXED, __HIP_MEMORY_SCOPE_AGENT);
            float a1 = __hip_atomic_load(&acc[1], __ATOMIC_RELAXED, __HIP_MEMORY_SCOPE_AGENT);
            float a2 = __hip_atomic_load(&acc[2], __ATOMIC_RELAXED, __HIP_MEMORY_SCOPE_AGENT);
            float a3 = __hip_atomic_load(&acc[3], __ATOMIC_RELAXED, __HIP_MEMORY_SCOPE_AGENT);
            out[0] = (5.0f * a0 + 0.5f * a2 + a1 + a3) * inv_batch;
        }
    }
}

extern "C" void kernel_launch(void* const* d_in, const int* in_sizes, int n_in,
                              void* d_out, int out_size, void* d_ws, size_t ws_size,
                              hipStream_t stream) {
    const float* P = (const float*)d_in[0];
    const float* T = (const float*)d_in[1];
    int ncell = in_sizes[0] / N_CH;                 // 25088
    int batch = ncell / (S_GRID * S_GRID);          // 512

    char* ws = (char*)d_ws;
    int*   hdr         = (int*)ws;
    float* acc         = (float*)(ws + 16);
    int*   finalCtr    = (int*)(ws + 48);
    int*   blockCounts = (int*)(ws + 64);
    int*   blockBase   = (int*)(ws + 576);
    float4* BP    = (float4*)(ws + 4096);
    float4* BT    = (float4*)(ws + 135168);
    float*  ConfP = (float*)(ws + 266240);
    float*  AreaP = (float*)(ws + 299008);
    unsigned long long* pkeys = (unsigned long long*)(ws + 331776);

    int nblk = (ncell + 255) / 256;                 // 98 (<=128 for the scan)
    k_count  <<<nblk, 256, 0, stream>>>(T, ncell, blockCounts, acc, finalCtr);
    k_scan   <<<1, 128, 0, stream>>>(blockCounts, blockBase, nblk, hdr);
    k_compact<<<nblk, 256, 0, stream>>>(P, T, ncell, blockBase, BP, BT, ConfP, AreaP, acc);
    dim3 g3(NTILE, NCHUNK);
    k_match  <<<g3, 256, 0, stream>>>(BP, BT, AreaP, hdr, pkeys);
    k_gather <<<NTILE, 256, 0, stream>>>(BP, BT, ConfP, hdr, pkeys,
                                         acc, finalCtr, (float*)d_out, 1.0f / (float)batch);
}